// Round 3
// baseline (338.087 us; speedup 1.0000x reference)
//
#include <hip/hip_runtime.h>

#define ANG 9
#define OHW 48
#define IMG 432
#define CIN 64
#define COUT 64
#define ND 9
#define NB 4
#define NVIEW 81
#define NSPAT 2304   // 48*48
#define NTOT 9216    // NB*NSPAT

using f32x4 = __attribute__((ext_vector_type(4))) float;
using s16x8 = __attribute__((ext_vector_type(8))) short;

__device__ __forceinline__ unsigned short f2bf(float f) {
    unsigned u = __float_as_uint(f);
    unsigned r = (u + 0x7FFFu + ((u >> 16) & 1u)) >> 16;   // RNE
    return (unsigned short)r;
}

// ---------------- kernel 1: pack W -> Aw[81][128][64] bf16 -------------------
// Aw[uv][co][ci]      = W[co][ci][u][v]          (var0, for d<=0)
// Aw[uv][64+co][ci]   = W[co][ci][8-u][8-v]      (var1, for d>0)
__global__ void k_wpack(const float* __restrict__ w, unsigned short* __restrict__ aw) {
    int idx = blockIdx.x * 256 + threadIdx.x;
    if (idx >= NVIEW * 128 * 64) return;
    int ci = idx & 63;
    int m  = (idx >> 6) & 127;
    int uv = idx >> 13;
    int u = uv / 9, v = uv % 9;
    int co = m & 63, var = m >> 6;
    int uu = var ? 8 - u : u;
    int vv = var ? 8 - v : v;
    aw[idx] = f2bf(w[((size_t)(co * 64 + ci) * 9 + uu) * 9 + vv]);
}

// ---------------- kernel 2: pack x -> xbT[81][9216][64] bf16 (v2) ------------
// xbT[u*9+v][b*2304 + h*48 + w][ci] = x[b][ci][9h+u][9w+v]
// Phase 1: float4-coalesced reads -> LDS [ci][iw] (stride 444, b64 writes).
// Phase 2: chunk order (v, wq, cig): 8 consecutive lanes write one contiguous
//          128B [n][0..63] run -> fully coalesced uint4 global stores.
#define LDSW 444
__global__ __launch_bounds__(256)
void k_packx2(const float* __restrict__ x, unsigned short* __restrict__ xbt) {
    __shared__ unsigned short lds[64 * LDSW];   // 56,832 B
    const int h = blockIdx.x, u = blockIdx.y, b = blockIdx.z;
    const int t = threadIdx.x;
    const int ih = 9 * h + u;

    // phase 1: 6912 float4 chunks = 64ci x 108 quads
    for (int g = t; g < 6912; g += 256) {
        const int ci = g / 108, j = g % 108;
        const float4 v4 = *reinterpret_cast<const float4*>(
            x + (((size_t)b * 64 + ci) * IMG + ih) * IMG + 4 * j);
        union { unsigned short us[4]; unsigned long long ll; } pk;
        pk.us[0] = f2bf(v4.x); pk.us[1] = f2bf(v4.y);
        pk.us[2] = f2bf(v4.z); pk.us[3] = f2bf(v4.w);
        *reinterpret_cast<unsigned long long*>(&lds[ci * LDSW + 4 * j]) = pk.ll;
    }
    __syncthreads();

    // phase 2: 3456 uint4 chunks = 9v x 48wq x 8cig
    const size_t obase0 = (size_t)u * 9 * NTOT + (size_t)b * NSPAT + (size_t)h * 48;
    for (int g = t; g < 3456; g += 256) {
        const int v   = g / 384, r = g % 384;
        const int wq  = r >> 3, cig = r & 7;
        const int iw  = 9 * wq + v;
        union { unsigned short us[8]; uint4 u4; } o;
#pragma unroll
        for (int c = 0; c < 8; ++c) o.us[c] = lds[(cig * 8 + c) * LDSW + iw];
        *reinterpret_cast<uint4*>(
            &xbt[((obase0 + (size_t)v * NTOT + wq) << 6) + cig * 8]) = o.u4;
    }
}

// ---------------- kernel 3: per-view GEMM, Y = Aw * xview --------------------
// Y[uv][co128][n] (bf16), M=128, N=9216, K=64.  16x16x32 bf16 MFMA.
__global__ __launch_bounds__(256)
void k_gemm(const unsigned short* __restrict__ aw,
            const unsigned short* __restrict__ xbt,
            unsigned short* __restrict__ y) {
    const int uv   = blockIdx.y;
    const int lane = threadIdx.x & 63;
    const int wave = threadIdx.x >> 6;
    const int n0   = blockIdx.x * 64 + wave * 16;
    const int lr   = lane & 15;
    const int lh   = lane >> 4;

    const unsigned short* bp = xbt + ((size_t)uv * NTOT + n0 + lr) * 64 + lh * 8;
    const s16x8 b0 = *reinterpret_cast<const s16x8*>(bp);
    const s16x8 b1 = *reinterpret_cast<const s16x8*>(bp + 32);

    f32x4 acc[8];
#pragma unroll
    for (int mf = 0; mf < 8; ++mf) acc[mf] = (f32x4){0.f, 0.f, 0.f, 0.f};

    const unsigned short* ab = aw + ((size_t)uv * 128 + lr) * 64 + lh * 8;
#pragma unroll
    for (int mf = 0; mf < 8; ++mf) {
        const s16x8 a0 = *reinterpret_cast<const s16x8*>(ab + (size_t)mf * 16 * 64);
        const s16x8 a1 = *reinterpret_cast<const s16x8*>(ab + (size_t)mf * 16 * 64 + 32);
        acc[mf] = __builtin_amdgcn_mfma_f32_16x16x32_bf16(a0, b0, acc[mf], 0, 0, 0);
        acc[mf] = __builtin_amdgcn_mfma_f32_16x16x32_bf16(a1, b1, acc[mf], 0, 0, 0);
    }

#pragma unroll
    for (int mf = 0; mf < 8; ++mf) {
#pragma unroll
        for (int r = 0; r < 4; ++r) {
            const int co = mf * 16 + lh * 4 + r;
            y[((size_t)uv * 128 + co) * NTOT + n0 + lr] = f2bf(acc[mf][r]);
        }
    }
}

// ---------------- kernel 4: shift-gather-sum over 81 views (v2) --------------
// out[b][co][dd][h][w] = sum_uv Y[uv][var(dd)*64+co][b][h-d'(u-4)][w-d'(v-4)]
// fp32 LDS slabs (zero-padded 80x80 per var); each thread owns 4 consecutive w
// -> adjacent-dword LDS reads (ds_read2/b64 mergeable) + float4 out stores.
__global__ __launch_bounds__(576)
void k_gather2(const unsigned short* __restrict__ y, float* __restrict__ out) {
    __shared__ float lds[2 * 80 * 80];   // 51,200 B
    const int co = blockIdx.x, b = blockIdx.y;
    const int tid = threadIdx.x;

    for (int i = tid; i < 2 * 80 * 80; i += 576) lds[i] = 0.f;

    const int var  = tid / 288;
    const int e0   = (tid % 288) * 8;
    const int srow = e0 / 48, scol = e0 % 48;
    const int ldst = var * 6400 + (16 + srow) * 80 + 16 + scol;
    const unsigned short* ybase =
        y + ((size_t)(var * 64 + co)) * NTOT + (size_t)b * NSPAT + e0;

    const int hh = tid / 12;          // 0..47
    const int w0 = (tid % 12) * 4;    // 0..44
    const int center = (16 + hh) * 80 + 16 + w0;

    float acc[9][4];
#pragma unroll
    for (int dd = 0; dd < 9; ++dd)
#pragma unroll
        for (int i = 0; i < 4; ++i) acc[dd][i] = 0.f;

    uint4 pre = *reinterpret_cast<const uint4*>(ybase);   // view 0
    __syncthreads();                                       // zero-fill done

    for (int uv = 0; uv < NVIEW; ++uv) {
        float4 lo, hi;
        lo.x = __uint_as_float(pre.x << 16);
        lo.y = __uint_as_float(pre.x & 0xffff0000u);
        lo.z = __uint_as_float(pre.y << 16);
        lo.w = __uint_as_float(pre.y & 0xffff0000u);
        hi.x = __uint_as_float(pre.z << 16);
        hi.y = __uint_as_float(pre.z & 0xffff0000u);
        hi.z = __uint_as_float(pre.w << 16);
        hi.w = __uint_as_float(pre.w & 0xffff0000u);
        *reinterpret_cast<float4*>(&lds[ldst])     = lo;
        *reinterpret_cast<float4*>(&lds[ldst + 4]) = hi;
        __syncthreads();
        if (uv < NVIEW - 1)
            pre = *reinterpret_cast<const uint4*>(ybase + (size_t)(uv + 1) * 128 * NTOT);

        const int uq = uv / 9, vq = uv % 9;
        const int step = (uq - 4) * 80 + (vq - 4);
        int base = center + 4 * step;                      // dd=0 -> +4*step
#pragma unroll
        for (int dd = 0; dd < 9; ++dd) {
            const float* p = &lds[base + (dd > 4 ? 6400 : 0)];
            acc[dd][0] += p[0];
            acc[dd][1] += p[1];
            acc[dd][2] += p[2];
            acc[dd][3] += p[3];
            base -= step;
        }
        __syncthreads();
    }

    const size_t ob = (size_t)(b * 64 + co) * 9 * NSPAT + tid * 4;
#pragma unroll
    for (int dd = 0; dd < 9; ++dd) {
        float4 o;
        o.x = acc[dd][0]; o.y = acc[dd][1]; o.z = acc[dd][2]; o.w = acc[dd][3];
        *reinterpret_cast<float4*>(&out[ob + (size_t)dd * NSPAT]) = o;
    }
}

// ---------------- fallback: round-1 direct conv (used if ws too small) -------
__global__ __launch_bounds__(192)
void cost_volume_direct(const float* __restrict__ x,
                        const float* __restrict__ w,
                        float* __restrict__ out) {
    const int ow      = threadIdx.x;
    const int oh      = blockIdx.y * 4 + threadIdx.y;
    const int co_tile = blockIdx.x & 7;
    const int dd      = blockIdx.x >> 3;
    const int b       = blockIdx.z;
    const int d       = dd - 4;
    const int co0     = co_tile * 8;

    int dilat, pad;
    if (d < 0)       { dilat = (-d) * ANG + 1; pad = 36 * (-d); }
    else if (d == 0) { dilat = 1;              pad = 0; }
    else             { dilat = d * ANG - 1;    pad = 36 * d - (ANG - 1); }

    const int ih0 = oh * ANG - pad;
    const int iw0 = ow * ANG - pad;

    float acc[8];
#pragma unroll
    for (int i = 0; i < 8; ++i) acc[i] = 0.f;

    const float* xb = x + (size_t)b * CIN * IMG * IMG;
    for (int kh = 0; kh < ANG; ++kh) {
        const int ih = ih0 + kh * dilat;
        if ((unsigned)ih >= (unsigned)IMG) continue;
        const float* xrow_base = xb + (size_t)ih * IMG;
        const float* wrow      = w + kh * ANG;
        for (int ci = 0; ci < CIN; ++ci) {
            const float* xrow = xrow_base + (size_t)ci * (IMG * IMG);
            float xv[ANG];
#pragma unroll
            for (int kw = 0; kw < ANG; ++kw) {
                const int iw  = iw0 + kw * dilat;
                const bool ok = ((unsigned)iw < (unsigned)IMG);
                const float vv = xrow[ok ? iw : 0];
                xv[kw] = ok ? vv : 0.f;
            }
            const float* wc = wrow + ci * (ANG * ANG);
#pragma unroll
            for (int i = 0; i < 8; ++i) {
                const float* wi = wc + (size_t)(co0 + i) * (CIN * ANG * ANG);
#pragma unroll
                for (int kw = 0; kw < ANG; ++kw)
                    acc[i] = fmaf(xv[kw], wi[kw], acc[i]);
            }
        }
    }
#pragma unroll
    for (int i = 0; i < 8; ++i) {
        const size_t o = ((((size_t)b * COUT + (co0 + i)) * ND + dd) * OHW + oh) * OHW + ow;
        out[o] = acc[i];
    }
}

extern "C" void kernel_launch(void* const* d_in, const int* in_sizes, int n_in,
                              void* d_out, int out_size, void* d_ws, size_t ws_size,
                              hipStream_t stream) {
    const float* x   = (const float*)d_in[0];
    const float* w   = (const float*)d_in[1];
    float*       out = (float*)d_out;

    const size_t AW_BYTES  = (size_t)NVIEW * 128 * 64 * 2;
    const size_t XBT_BYTES = (size_t)NVIEW * NTOT * 64 * 2;
    const size_t Y_BYTES   = (size_t)NVIEW * 128 * NTOT * 2;
    const size_t NEED      = AW_BYTES + XBT_BYTES + Y_BYTES;   // ~288 MB

    if (ws_size >= NEED) {
        unsigned short* aw  = (unsigned short*)d_ws;
        unsigned short* xbt = (unsigned short*)((char*)d_ws + AW_BYTES);
        unsigned short* yb  = (unsigned short*)((char*)d_ws + AW_BYTES + XBT_BYTES);

        k_wpack <<<dim3((NVIEW * 128 * 64 + 255) / 256), dim3(256), 0, stream>>>(w, aw);
        k_packx2<<<dim3(OHW, ANG, NB), dim3(256), 0, stream>>>(x, xbt);
        k_gemm  <<<dim3(NTOT / 64, NVIEW), dim3(256), 0, stream>>>(aw, xbt, yb);
        k_gather2<<<dim3(COUT, NB), dim3(576), 0, stream>>>(yb, out);
    } else {
        dim3 grid(8 * ND, OHW / 4, NB);
        dim3 block(OHW, 4, 1);
        cost_volume_direct<<<grid, block, 0, stream>>>(x, w, out);
    }
}

// Round 4
// 285.967 us; speedup vs baseline: 1.1823x; 1.1823x over previous
//
#include <hip/hip_runtime.h>

#define ANG 9
#define OHW 48
#define IMG 432
#define CIN 64
#define COUT 64
#define ND 9
#define NB 4
#define NVIEW 81
#define NSPAT 2304   // 48*48
#define NTOT 9216    // NB*NSPAT

using f32x4 = __attribute__((ext_vector_type(4))) float;
using s16x8 = __attribute__((ext_vector_type(8))) short;

__device__ __forceinline__ unsigned short f2bf(float f) {
    unsigned u = __float_as_uint(f);
    unsigned r = (u + 0x7FFFu + ((u >> 16) & 1u)) >> 16;   // RNE
    return (unsigned short)r;
}

// ---------------- kernel 1: pack W -> Aw[81][128][64] bf16 -------------------
// Aw[uv][co][ci]      = W[co][ci][u][v]          (var0, for d<=0)
// Aw[uv][64+co][ci]   = W[co][ci][8-u][8-v]      (var1, for d>0)
__global__ void k_wpack(const float* __restrict__ w, unsigned short* __restrict__ aw) {
    int idx = blockIdx.x * 256 + threadIdx.x;
    if (idx >= NVIEW * 128 * 64) return;
    int ci = idx & 63;
    int m  = (idx >> 6) & 127;
    int uv = idx >> 13;
    int u = uv / 9, v = uv % 9;
    int co = m & 63, var = m >> 6;
    int uu = var ? 8 - u : u;
    int vv = var ? 8 - v : v;
    aw[idx] = f2bf(w[((size_t)(co * 64 + ci) * 9 + uu) * 9 + vv]);
}

// ---------------- kernel 2: fused pack + per-view GEMM -----------------------
// Block (h, u, b): stage x[b][:][9h+u][:] as bf16 LDS [iw][ci] (XOR-swizzled),
// then 54 MFMA tasks = 9 v-views x 3 n-tiles x 2 co-halves.
// Y[uv][m=var*64+co][n = b*2304 + h*48 + w] bf16, via mfma_f32_16x16x32_bf16.
__global__ __launch_bounds__(512, 4)
void k_fused(const float* __restrict__ x,
             const unsigned short* __restrict__ aw,
             unsigned short* __restrict__ y) {
    __shared__ unsigned short lx[IMG * 64];   // 55,296 B, [iw][ci^swz]
    const int h = blockIdx.x, u = blockIdx.y, b = blockIdx.z;
    const int t = threadIdx.x;
    const int ih = 9 * h + u;

    // ---- stage: coalesced float4 reads, bf16 scalar LDS writes (swizzled) ----
    {
        const int tx = t & 127, ty = t >> 7;   // tx: iw-quad, ty: ci-group
        if (tx < 108) {
            const float* base = x + (((size_t)b * 64) * IMG + ih) * IMG + 4 * tx;
#pragma unroll 4
            for (int k = 0; k < 16; ++k) {
                const int ci = ty * 16 + k;
                const float4 v4 = *reinterpret_cast<const float4*>(
                    base + (size_t)ci * (IMG * IMG));
                unsigned short us[4] = {f2bf(v4.x), f2bf(v4.y), f2bf(v4.z), f2bf(v4.w)};
#pragma unroll
                for (int jj = 0; jj < 4; ++jj) {
                    const int iw = 4 * tx + jj;
                    const int sc = ci ^ (((iw >> 2) & 7) << 3);
                    lx[iw * 64 + sc] = us[jj];
                }
            }
        }
    }
    __syncthreads();

    // ---- compute: 54 wave-tasks over 8 waves ----
    const int lane = t & 63, wave = t >> 6;
    const int lr = lane & 15;   // n/m row selector
    const int lh = lane >> 4;   // k-group selector

    for (int idx = wave; idx < 54; idx += 8) {
        const int v  = idx / 6;
        const int r6 = idx % 6;
        const int nt = r6 >> 1;
        const int mh = r6 & 1;
        const int uv = u * 9 + v;

        // B fragments from LDS (swizzled, 16B-aligned b128 reads)
        const int iw = 9 * (nt * 16 + lr) + v;
        const int g  = (iw >> 2) & 7;
        const s16x8 b0 = *reinterpret_cast<const s16x8*>(&lx[iw * 64 + ((lh ^ g) * 8)]);
        const s16x8 b1 = *reinterpret_cast<const s16x8*>(&lx[iw * 64 + (((4 + lh) ^ g) * 8)]);

        // A fragments from global (L2-hot)
        const unsigned short* ab =
            aw + ((size_t)uv * 128 + mh * 64 + lr) * 64 + lh * 8;

        f32x4 acc[4];
#pragma unroll
        for (int mf = 0; mf < 4; ++mf) acc[mf] = (f32x4){0.f, 0.f, 0.f, 0.f};

#pragma unroll
        for (int mf = 0; mf < 4; ++mf) {
            const s16x8 a0 = *reinterpret_cast<const s16x8*>(ab + (size_t)mf * 16 * 64);
            const s16x8 a1 = *reinterpret_cast<const s16x8*>(ab + (size_t)mf * 16 * 64 + 32);
            acc[mf] = __builtin_amdgcn_mfma_f32_16x16x32_bf16(a0, b0, acc[mf], 0, 0, 0);
            acc[mf] = __builtin_amdgcn_mfma_f32_16x16x32_bf16(a1, b1, acc[mf], 0, 0, 0);
        }

        // D layout: col = lane&15, row = (lane>>4)*4 + reg  [m89-verified]
        const int n0 = b * NSPAT + h * 48 + nt * 16;
#pragma unroll
        for (int mf = 0; mf < 4; ++mf) {
#pragma unroll
            for (int rr = 0; rr < 4; ++rr) {
                const int m = mh * 64 + mf * 16 + lh * 4 + rr;
                y[((size_t)uv * 128 + m) * NTOT + n0 + lr] = f2bf(acc[mf][rr]);
            }
        }
    }
}

// ---------------- kernel 3: shift-gather-sum over 81 views (v3) --------------
// out[b][co][dd][h][w] = sum_uv Y[uv][var(dd)*64+co][b][h-d'(u-4)][w-d'(v-4)]
// Double-buffered fp32 slabs (2 x 2 x 80x80), ONE barrier per view,
// prefetch depth 2.
__global__ __launch_bounds__(576, 2)
void k_gather3(const unsigned short* __restrict__ y, float* __restrict__ out) {
    __shared__ float lds[2][2 * 80 * 80];   // 102,400 B
    const int co = blockIdx.x, b = blockIdx.y;
    const int tid = threadIdx.x;

    for (int i = tid; i < 2 * 2 * 80 * 80; i += 576)
        ((float*)lds)[i] = 0.f;

    const int var  = tid / 288;
    const int e0   = (tid % 288) * 8;
    const int srow = e0 / 48, scol = e0 % 48;
    const int ldst = var * 6400 + (16 + srow) * 80 + 16 + scol;
    const unsigned short* ybase =
        y + ((size_t)(var * 64 + co)) * NTOT + (size_t)b * NSPAT + e0;

    const int hh = tid / 12;          // 0..47
    const int w0 = (tid % 12) * 4;    // 0..44
    const int center = (16 + hh) * 80 + 16 + w0;

    float acc[9][4];
#pragma unroll
    for (int dd = 0; dd < 9; ++dd)
#pragma unroll
        for (int i = 0; i < 4; ++i) acc[dd][i] = 0.f;

    uint4 pre0 = *reinterpret_cast<const uint4*>(ybase);                         // uv=0
    uint4 pre1 = *reinterpret_cast<const uint4*>(ybase + (size_t)128 * NTOT);    // uv=1
    __syncthreads();   // zero-fill done

    for (int uv = 0; uv < NVIEW; ++uv) {
        float* slab = lds[uv & 1];
        float4 lo, hi;
        lo.x = __uint_as_float(pre0.x << 16);
        lo.y = __uint_as_float(pre0.x & 0xffff0000u);
        lo.z = __uint_as_float(pre0.y << 16);
        lo.w = __uint_as_float(pre0.y & 0xffff0000u);
        hi.x = __uint_as_float(pre0.z << 16);
        hi.y = __uint_as_float(pre0.z & 0xffff0000u);
        hi.z = __uint_as_float(pre0.w << 16);
        hi.w = __uint_as_float(pre0.w & 0xffff0000u);
        *reinterpret_cast<float4*>(&slab[ldst])     = lo;
        *reinterpret_cast<float4*>(&slab[ldst + 4]) = hi;

        pre0 = pre1;
        if (uv + 2 < NVIEW)
            pre1 = *reinterpret_cast<const uint4*>(ybase + (size_t)(uv + 2) * 128 * NTOT);

        __syncthreads();   // slab[uv&1] complete (prev compute of other buf already done)

        const int uq = uv / 9, vq = uv % 9;
        const int step = (uq - 4) * 80 + (vq - 4);
        int base = center + 4 * step;                  // dd=0 -> +4*step
#pragma unroll
        for (int dd = 0; dd < 9; ++dd) {
            const float* p = &slab[base + (dd > 4 ? 6400 : 0)];
            acc[dd][0] += p[0];
            acc[dd][1] += p[1];
            acc[dd][2] += p[2];
            acc[dd][3] += p[3];
            base -= step;
        }
        // no second barrier: next iter writes the OTHER buffer; this buffer is
        // only rewritten at uv+2, after the uv+1 barrier.
    }

    const size_t ob = (size_t)(b * 64 + co) * 9 * NSPAT + tid * 4;
#pragma unroll
    for (int dd = 0; dd < 9; ++dd) {
        float4 o;
        o.x = acc[dd][0]; o.y = acc[dd][1]; o.z = acc[dd][2]; o.w = acc[dd][3];
        *reinterpret_cast<float4*>(&out[ob + (size_t)dd * NSPAT]) = o;
    }
}

// ---------------- fallback: round-1 direct conv (used if ws too small) -------
__global__ __launch_bounds__(192)
void cost_volume_direct(const float* __restrict__ x,
                        const float* __restrict__ w,
                        float* __restrict__ out) {
    const int ow      = threadIdx.x;
    const int oh      = blockIdx.y * 4 + threadIdx.y;
    const int co_tile = blockIdx.x & 7;
    const int dd      = blockIdx.x >> 3;
    const int b       = blockIdx.z;
    const int d       = dd - 4;
    const int co0     = co_tile * 8;

    int dilat, pad;
    if (d < 0)       { dilat = (-d) * ANG + 1; pad = 36 * (-d); }
    else if (d == 0) { dilat = 1;              pad = 0; }
    else             { dilat = d * ANG - 1;    pad = 36 * d - (ANG - 1); }

    const int ih0 = oh * ANG - pad;
    const int iw0 = ow * ANG - pad;

    float acc[8];
#pragma unroll
    for (int i = 0; i < 8; ++i) acc[i] = 0.f;

    const float* xb = x + (size_t)b * CIN * IMG * IMG;
    for (int kh = 0; kh < ANG; ++kh) {
        const int ih = ih0 + kh * dilat;
        if ((unsigned)ih >= (unsigned)IMG) continue;
        const float* xrow_base = xb + (size_t)ih * IMG;
        const float* wrow      = w + kh * ANG;
        for (int ci = 0; ci < CIN; ++ci) {
            const float* xrow = xrow_base + (size_t)ci * (IMG * IMG);
            float xv[ANG];
#pragma unroll
            for (int kw = 0; kw < ANG; ++kw) {
                const int iw  = iw0 + kw * dilat;
                const bool ok = ((unsigned)iw < (unsigned)IMG);
                const float vv = xrow[ok ? iw : 0];
                xv[kw] = ok ? vv : 0.f;
            }
            const float* wc = wrow + ci * (ANG * ANG);
#pragma unroll
            for (int i = 0; i < 8; ++i) {
                const float* wi = wc + (size_t)(co0 + i) * (CIN * ANG * ANG);
#pragma unroll
                for (int kw = 0; kw < ANG; ++kw)
                    acc[i] = fmaf(xv[kw], wi[kw], acc[i]);
            }
        }
    }
#pragma unroll
    for (int i = 0; i < 8; ++i) {
        const size_t o = ((((size_t)b * COUT + (co0 + i)) * ND + dd) * OHW + oh) * OHW + ow;
        out[o] = acc[i];
    }
}

extern "C" void kernel_launch(void* const* d_in, const int* in_sizes, int n_in,
                              void* d_out, int out_size, void* d_ws, size_t ws_size,
                              hipStream_t stream) {
    const float* x   = (const float*)d_in[0];
    const float* w   = (const float*)d_in[1];
    float*       out = (float*)d_out;

    const size_t AW_BYTES = (size_t)NVIEW * 128 * 64 * 2;        //   1,327,104
    const size_t Y_BYTES  = (size_t)NVIEW * 128 * NTOT * 2;      // 191,102,976
    const size_t NEED     = AW_BYTES + Y_BYTES;                  // ~192.4 MB

    if (ws_size >= NEED) {
        unsigned short* aw = (unsigned short*)d_ws;
        unsigned short* yb = (unsigned short*)((char*)d_ws + AW_BYTES);

        k_wpack  <<<dim3((NVIEW * 128 * 64 + 255) / 256), dim3(256), 0, stream>>>(w, aw);
        k_fused  <<<dim3(OHW, ANG, NB), dim3(512), 0, stream>>>(x, aw, yb);
        k_gather3<<<dim3(COUT, NB), dim3(576), 0, stream>>>(yb, out);
    } else {
        dim3 grid(8 * ND, OHW / 4, NB);
        dim3 block(OHW, 4, 1);
        cost_volume_direct<<<grid, block, 0, stream>>>(x, w, out);
    }
}

// Round 5
// 223.423 us; speedup vs baseline: 1.5132x; 1.2799x over previous
//
#include <hip/hip_runtime.h>

#define ANG 9
#define OHW 48
#define IMG 432
#define CIN 64
#define COUT 64
#define ND 9
#define NB 4
#define NVIEW 81
#define NSPAT 2304   // 48*48
#define NTOT 9216    // NB*NSPAT

#define SLABW 81                 // padded slab row stride (80 -> 81): breaks 8-way LDS bank conflict
#define SLABSZ (80 * SLABW)      // 6480 floats per var-slab

using f32x4 = __attribute__((ext_vector_type(4))) float;
using s16x8 = __attribute__((ext_vector_type(8))) short;

__device__ __forceinline__ unsigned short f2bf(float f) {
    unsigned u = __float_as_uint(f);
    unsigned r = (u + 0x7FFFu + ((u >> 16) & 1u)) >> 16;   // RNE
    return (unsigned short)r;
}

// ---------------- kernel 1: pack W -> Aw[81][128][64] bf16 -------------------
// Aw[uv][co][ci]      = W[co][ci][u][v]          (var0, for d<=0)
// Aw[uv][64+co][ci]   = W[co][ci][8-u][8-v]      (var1, for d>0)
__global__ void k_wpack(const float* __restrict__ w, unsigned short* __restrict__ aw) {
    int idx = blockIdx.x * 256 + threadIdx.x;
    if (idx >= NVIEW * 128 * 64) return;
    int ci = idx & 63;
    int m  = (idx >> 6) & 127;
    int uv = idx >> 13;
    int u = uv / 9, v = uv % 9;
    int co = m & 63, var = m >> 6;
    int uu = var ? 8 - u : u;
    int vv = var ? 8 - v : v;
    aw[idx] = f2bf(w[((size_t)(co * 64 + ci) * 9 + uu) * 9 + vv]);
}

// ---------------- kernel 2: fused pack + per-view GEMM (v2) ------------------
// Block (h, u, b): stage x[b][:][9h+u][:] as bf16 LDS [iw][ci^swz], then each
// wave owns a fixed (mh, mf) 16-row tile and loops v(9) x nt(3), fully
// unrolled: pure {2 ds_read_b128 -> 2 MFMA -> 4 stores} independent bodies.
// A-frags a0[9] preloaded to registers BEFORE the staging barrier.
__global__ __launch_bounds__(512, 4)
void k_fused(const float* __restrict__ x,
             const unsigned short* __restrict__ aw,
             unsigned short* __restrict__ y) {
    __shared__ unsigned short lx[IMG * 64];   // 55,296 B, [iw][ci^swz]
    const int h = blockIdx.x, u = blockIdx.y, b = blockIdx.z;
    const int t = threadIdx.x;
    const int ih = 9 * h + u;
    const int lane = t & 63, wave = t >> 6;
    const int lr = lane & 15;   // n/m row selector
    const int lh = lane >> 4;   // k-group selector
    const int mh = wave >> 2;   // 0..1  (co-variant half)
    const int mf = wave & 3;    // 0..3  (16-row tile within the 64-row half)

    // ---- A-preload (overlaps staging; independent of LDS) ----
    const unsigned short* abase =
        aw + (((size_t)(u * 9) * 128) + mh * 64 + mf * 16 + lr) * 64 + lh * 8;
    s16x8 a0[9];
#pragma unroll
    for (int v = 0; v < 9; ++v)
        a0[v] = *reinterpret_cast<const s16x8*>(abase + (size_t)v * 128 * 64);

    // ---- stage: coalesced float4 reads, bf16 scalar LDS writes (swizzled) ----
    {
        const int tx = t & 127, ty = t >> 7;   // tx: iw-quad, ty: ci-group
        if (tx < 108) {
            const float* base = x + (((size_t)b * 64) * IMG + ih) * IMG + 4 * tx;
#pragma unroll 4
            for (int k = 0; k < 16; ++k) {
                const int ci = ty * 16 + k;
                const float4 v4 = *reinterpret_cast<const float4*>(
                    base + (size_t)ci * (IMG * IMG));
                unsigned short us[4] = {f2bf(v4.x), f2bf(v4.y), f2bf(v4.z), f2bf(v4.w)};
#pragma unroll
                for (int jj = 0; jj < 4; ++jj) {
                    const int iw = 4 * tx + jj;
                    const int sc = ci ^ (((iw >> 2) & 7) << 3);
                    lx[iw * 64 + sc] = us[jj];
                }
            }
        }
    }
    __syncthreads();

    // ---- compute: 27 fully-unrolled independent tile bodies ----
#pragma unroll
    for (int v = 0; v < 9; ++v) {
        const int uv = u * 9 + v;
        // a1 (k=32..63 half): loaded once per v, reused 3x, L2-hot
        const s16x8 a1 = *reinterpret_cast<const s16x8*>(
            abase + (size_t)v * 128 * 64 + 32);
#pragma unroll
        for (int nt = 0; nt < 3; ++nt) {
            const int iw = 9 * (nt * 16 + lr) + v;
            const int g  = (iw >> 2) & 7;
            const s16x8 b0 = *reinterpret_cast<const s16x8*>(&lx[iw * 64 + ((lh ^ g) * 8)]);
            const s16x8 b1 = *reinterpret_cast<const s16x8*>(&lx[iw * 64 + (((4 + lh) ^ g) * 8)]);

            f32x4 acc = (f32x4){0.f, 0.f, 0.f, 0.f};
            acc = __builtin_amdgcn_mfma_f32_16x16x32_bf16(a0[v], b0, acc, 0, 0, 0);
            acc = __builtin_amdgcn_mfma_f32_16x16x32_bf16(a1,    b1, acc, 0, 0, 0);

            // D layout: col = lane&15, row = (lane>>4)*4 + reg  [m89-verified]
            const int n0 = b * NSPAT + h * 48 + nt * 16;
#pragma unroll
            for (int rr = 0; rr < 4; ++rr) {
                const int m = mh * 64 + mf * 16 + lh * 4 + rr;
                y[((size_t)uv * 128 + m) * NTOT + n0 + lr] = f2bf(acc[rr]);
            }
        }
    }
}

// ---------------- kernel 3: shift-gather-sum over 81 views (v4) --------------
// out[b][co][dd][h][w] = sum_uv Y[uv][var(dd)*64+co][b][h-d'(u-4)][w-d'(v-4)]
// Single-buffer padded fp32 slabs (2 x 80 x 81), 2 barriers/view,
// prefetch depth 2. Pad-81 spreads the stride-4-dword read pattern over
// ~all banks (was 8-way conflict at width 80).
__global__ __launch_bounds__(576)
void k_gather4(const unsigned short* __restrict__ y, float* __restrict__ out) {
    __shared__ float lds[2 * SLABSZ];   // 51,840 B
    const int co = blockIdx.x, b = blockIdx.y;
    const int tid = threadIdx.x;

    for (int i = tid; i < 2 * SLABSZ; i += 576) lds[i] = 0.f;

    const int var  = tid / 288;
    const int e0   = (tid % 288) * 8;
    const int srow = e0 / 48, scol = e0 % 48;
    const int ldst = var * SLABSZ + (16 + srow) * SLABW + 16 + scol;
    const unsigned short* ybase =
        y + ((size_t)(var * 64 + co)) * NTOT + (size_t)b * NSPAT + e0;

    const int hh = tid / 12;          // 0..47
    const int w0 = (tid % 12) * 4;    // 0..44
    const int center = (16 + hh) * SLABW + 16 + w0;

    float acc[9][4];
#pragma unroll
    for (int dd = 0; dd < 9; ++dd)
#pragma unroll
        for (int i = 0; i < 4; ++i) acc[dd][i] = 0.f;

    uint4 pre0 = *reinterpret_cast<const uint4*>(ybase);                        // uv=0
    uint4 pre1 = *reinterpret_cast<const uint4*>(ybase + (size_t)128 * NTOT);   // uv=1
    __syncthreads();   // zero-fill done

    for (int uv = 0; uv < NVIEW; ++uv) {
        float4 lo, hi;
        lo.x = __uint_as_float(pre0.x << 16);
        lo.y = __uint_as_float(pre0.x & 0xffff0000u);
        lo.z = __uint_as_float(pre0.y << 16);
        lo.w = __uint_as_float(pre0.y & 0xffff0000u);
        hi.x = __uint_as_float(pre0.z << 16);
        hi.y = __uint_as_float(pre0.z & 0xffff0000u);
        hi.z = __uint_as_float(pre0.w << 16);
        hi.w = __uint_as_float(pre0.w & 0xffff0000u);
        *reinterpret_cast<float4*>(&lds[ldst])     = lo;
        *reinterpret_cast<float4*>(&lds[ldst + 4]) = hi;

        pre0 = pre1;
        if (uv + 2 < NVIEW)
            pre1 = *reinterpret_cast<const uint4*>(ybase + (size_t)(uv + 2) * 128 * NTOT);

        __syncthreads();   // slab complete

        const int uq = uv / 9, vq = uv % 9;
        const int step = (uq - 4) * SLABW + (vq - 4);
        int base = center + 4 * step;                  // dd=0 -> +4*step
#pragma unroll
        for (int dd = 0; dd < 9; ++dd) {
            const float* p = &lds[base + (dd > 4 ? SLABSZ : 0)];
            acc[dd][0] += p[0];
            acc[dd][1] += p[1];
            acc[dd][2] += p[2];
            acc[dd][3] += p[3];
            base -= step;
        }
        __syncthreads();   // reads done before next view's writes
    }

    const size_t ob = (size_t)(b * 64 + co) * 9 * NSPAT + tid * 4;
#pragma unroll
    for (int dd = 0; dd < 9; ++dd) {
        float4 o;
        o.x = acc[dd][0]; o.y = acc[dd][1]; o.z = acc[dd][2]; o.w = acc[dd][3];
        *reinterpret_cast<float4*>(&out[ob + (size_t)dd * NSPAT]) = o;
    }
}

// ---------------- fallback: round-1 direct conv (used if ws too small) -------
__global__ __launch_bounds__(192)
void cost_volume_direct(const float* __restrict__ x,
                        const float* __restrict__ w,
                        float* __restrict__ out) {
    const int ow      = threadIdx.x;
    const int oh      = blockIdx.y * 4 + threadIdx.y;
    const int co_tile = blockIdx.x & 7;
    const int dd      = blockIdx.x >> 3;
    const int b       = blockIdx.z;
    const int d       = dd - 4;
    const int co0     = co_tile * 8;

    int dilat, pad;
    if (d < 0)       { dilat = (-d) * ANG + 1; pad = 36 * (-d); }
    else if (d == 0) { dilat = 1;              pad = 0; }
    else             { dilat = d * ANG - 1;    pad = 36 * d - (ANG - 1); }

    const int ih0 = oh * ANG - pad;
    const int iw0 = ow * ANG - pad;

    float acc[8];
#pragma unroll
    for (int i = 0; i < 8; ++i) acc[i] = 0.f;

    const float* xb = x + (size_t)b * CIN * IMG * IMG;
    for (int kh = 0; kh < ANG; ++kh) {
        const int ih = ih0 + kh * dilat;
        if ((unsigned)ih >= (unsigned)IMG) continue;
        const float* xrow_base = xb + (size_t)ih * IMG;
        const float* wrow      = w + kh * ANG;
        for (int ci = 0; ci < CIN; ++ci) {
            const float* xrow = xrow_base + (size_t)ci * (IMG * IMG);
            float xv[ANG];
#pragma unroll
            for (int kw = 0; kw < ANG; ++kw) {
                const int iw  = iw0 + kw * dilat;
                const bool ok = ((unsigned)iw < (unsigned)IMG);
                const float vv = xrow[ok ? iw : 0];
                xv[kw] = ok ? vv : 0.f;
            }
            const float* wc = wrow + ci * (ANG * ANG);
#pragma unroll
            for (int i = 0; i < 8; ++i) {
                const float* wi = wc + (size_t)(co0 + i) * (CIN * ANG * ANG);
#pragma unroll
                for (int kw = 0; kw < ANG; ++kw)
                    acc[i] = fmaf(xv[kw], wi[kw], acc[i]);
            }
        }
    }
#pragma unroll
    for (int i = 0; i < 8; ++i) {
        const size_t o = ((((size_t)b * COUT + (co0 + i)) * ND + dd) * OHW + oh) * OHW + ow;
        out[o] = acc[i];
    }
}

extern "C" void kernel_launch(void* const* d_in, const int* in_sizes, int n_in,
                              void* d_out, int out_size, void* d_ws, size_t ws_size,
                              hipStream_t stream) {
    const float* x   = (const float*)d_in[0];
    const float* w   = (const float*)d_in[1];
    float*       out = (float*)d_out;

    const size_t AW_BYTES = (size_t)NVIEW * 128 * 64 * 2;        //   1,327,104
    const size_t Y_BYTES  = (size_t)NVIEW * 128 * NTOT * 2;      // 191,102,976
    const size_t NEED     = AW_BYTES + Y_BYTES;                  // ~192.4 MB

    if (ws_size >= NEED) {
        unsigned short* aw = (unsigned short*)d_ws;
        unsigned short* yb = (unsigned short*)((char*)d_ws + AW_BYTES);

        k_wpack  <<<dim3((NVIEW * 128 * 64 + 255) / 256), dim3(256), 0, stream>>>(w, aw);
        k_fused  <<<dim3(OHW, ANG, NB), dim3(512), 0, stream>>>(x, aw, yb);
        k_gather4<<<dim3(COUT, NB), dim3(576), 0, stream>>>(yb, out);
    } else {
        dim3 grid(8 * ND, OHW / 4, NB);
        dim3 block(OHW, 4, 1);
        cost_volume_direct<<<grid, block, 0, stream>>>(x, w, out);
    }
}